// Round 5
// baseline (364.827 us; speedup 1.0000x reference)
//
#include <hip/hip_runtime.h>
#include <stdint.h>

#define NPIX 9216   // 96*96
#define NIMG 32
#define STRIP 1152  // NPIX / 8 subs
#define MAGIC 0x5EED5EED

// ---------- JAX threefry2x32 (20 rounds), bit-exact (verified rounds 1-4) ----------
__device__ __forceinline__ uint32_t rotl32(uint32_t x, int d){ return (x<<d)|(x>>(32-d)); }

__device__ __forceinline__ void threefry(uint32_t k0, uint32_t k1, uint32_t x0, uint32_t x1,
                                         uint32_t &o0, uint32_t &o1){
  uint32_t ks2 = k0 ^ k1 ^ 0x1BD11BDAu;
  x0 += k0; x1 += k1;
  x0+=x1; x1=rotl32(x1,13); x1^=x0;
  x0+=x1; x1=rotl32(x1,15); x1^=x0;
  x0+=x1; x1=rotl32(x1,26); x1^=x0;
  x0+=x1; x1=rotl32(x1,6);  x1^=x0;
  x0+=k1; x1+=ks2+1u;
  x0+=x1; x1=rotl32(x1,17); x1^=x0;
  x0+=x1; x1=rotl32(x1,29); x1^=x0;
  x0+=x1; x1=rotl32(x1,16); x1^=x0;
  x0+=x1; x1=rotl32(x1,24); x1^=x0;
  x0+=ks2; x1+=k0+2u;
  x0+=x1; x1=rotl32(x1,13); x1^=x0;
  x0+=x1; x1=rotl32(x1,15); x1^=x0;
  x0+=x1; x1=rotl32(x1,26); x1^=x0;
  x0+=x1; x1=rotl32(x1,6);  x1^=x0;
  x0+=k0; x1+=k1+3u;
  x0+=x1; x1=rotl32(x1,17); x1^=x0;
  x0+=x1; x1=rotl32(x1,29); x1^=x0;
  x0+=x1; x1=rotl32(x1,16); x1^=x0;
  x0+=x1; x1=rotl32(x1,24); x1^=x0;
  x0+=k1; x1+=ks2+4u;
  x0+=x1; x1=rotl32(x1,13); x1^=x0;
  x0+=x1; x1=rotl32(x1,15); x1^=x0;
  x0+=x1; x1=rotl32(x1,26); x1^=x0;
  x0+=x1; x1=rotl32(x1,6);  x1^=x0;
  x0+=ks2; x1+=k0+5u;
  o0=x0; o1=x1;
}

__device__ __forceinline__ float clip01_div255(float x){
  return fminf(fmaxf(x/255.0f, 0.0f), 1.0f);
}

// Single fused kernel: 512 blocks x 512 threads, all co-resident by construction
// (launch_bounds(512,4) => VGPR<=128 => 4 waves/SIMD => 2 blocks/CU x 256 CU = 512).
// Flag-pipelined phases; flags start at 0xAAAAAAAA poison != MAGIC.
__global__ __launch_bounds__(512, 4) void kfused(const float* __restrict__ in,
                                                 float* __restrict__ out,
                                                 float* __restrict__ maxpart,  // [32][8][3]
                                                 int* __restrict__ flagA,      // [32*8]
                                                 int* __restrict__ flagB,      // [512]
                                                 int* __restrict__ flagC,      // [32]
                                                 unsigned long long* __restrict__ key50g, // [512][50]
                                                 float* __restrict__ train_s,  // [32][100][5]
                                                 float* __restrict__ meanstd){ // [32][10]
#pragma clang fp contract(off)
  int b   = blockIdx.x;
  int tid = threadIdx.x;
  int pair = b >> 3, sub = b & 7;       // pair 0..63, sub 0..7
  int img  = pair >> 1, cls = pair & 1; // cls: 0 = fg, 1 = bg
  int lane = tid & 63, wv = tid >> 6;

  __shared__ float    pixL[3456];       // strip pixels (13.8 KB), reused in P3
  __shared__ uint32_t vvL[STRIP];
  __shared__ uint64_t cand[STRIP];      // reused as key-merge buffer in P2
  __shared__ int      hist[129];
  __shared__ int      ncand, bbin;
  __shared__ float    red[3][8];
  __shared__ float    bcast[3];
  __shared__ float    feat[100][5];
  __shared__ int      tIdxL[100];
  __shared__ float    mv[5], sv[5];
  __shared__ float    ts[100][8];       // padded rows for float4 reads

  if(tid < 129) hist[tid] = 0;
  if(tid == 0)  ncand = 0;

  // ================= P0: stage strip; cls0 blocks emit channel-max partial ========
  const float* sp = in + ((size_t)img*NPIX + (size_t)sub*STRIP)*3;
  for(int k=0;k<7;k++){ int idx=k*512+tid; if(idx<3456) pixL[idx]=sp[idx]; }
  __syncthreads();

  if(cls==0){
    float m0=0.f,m1=0.f,m2=0.f;
    for(int r=0;r<3;r++){
      int pi = tid + r*512;
      if(pi<STRIP){
        m0=fmaxf(m0, clip01_div255(pixL[pi*3+0]));
        m1=fmaxf(m1, clip01_div255(pixL[pi*3+1]));
        m2=fmaxf(m2, clip01_div255(pixL[pi*3+2]));
      }
    }
    for(int off=32;off>0;off>>=1){
      m0=fmaxf(m0,__shfl_down(m0,off));
      m1=fmaxf(m1,__shfl_down(m1,off));
      m2=fmaxf(m2,__shfl_down(m2,off));
    }
    if(lane==0){ red[0][wv]=m0; red[1][wv]=m1; red[2][wv]=m2; }
    __syncthreads();
    if(tid==0){
      float a=red[0][0], bb2=red[1][0], c=red[2][0];
      for(int w=1;w<8;w++){ a=fmaxf(a,red[0][w]); bb2=fmaxf(bb2,red[1][w]); c=fmaxf(c,red[2][w]); }
      maxpart[(img*8+sub)*3+0]=a;
      maxpart[(img*8+sub)*3+1]=bb2;
      maxpart[(img*8+sub)*3+2]=c;
      __threadfence();
      atomicExch(&flagA[img*8+sub], MAGIC);
    }
  }

  // ================= P1: full-image max -> score own strip -> exact local top-50 ===
  if(tid<8){ while(atomicAdd(&flagA[img*8+tid],0)!=MAGIC) __builtin_amdgcn_s_sleep(2); }
  __syncthreads();
  __threadfence();
  if(tid==0){
    float a=0.f,bb2=0.f,c=0.f;
    for(int s=0;s<8;s++){
      a  =fmaxf(a,  maxpart[(img*8+s)*3+0]);
      bb2=fmaxf(bb2,maxpart[(img*8+s)*3+1]);
      c  =fmaxf(c,  maxpart[(img*8+s)*3+2]);
    }
    bcast[0]=a; bcast[1]=bb2; bcast[2]=c;
  }
  __syncthreads();
  float c0=bcast[0], c1=bcast[1], c2=bcast[2];

  // partitionable threefry keys (bit-exact)
  uint32_t ik0, ik1; threefry(0u, 42u, 0u, (uint32_t)img, ik0, ik1);
  uint32_t s0, s1;   threefry(ik0, ik1, 0u, (uint32_t)cls, s0, s1);

  for(int r=0;r<3;r++){
    int pi = tid + r*512;
    if(pi<STRIP){
      float a  = clip01_div255(pixL[pi*3+0])/c0;
      float bb2= clip01_div255(pixL[pi*3+1])/c1;
      float c  = clip01_div255(pixL[pi*3+2])/c2;
      bool fg = (a>0.f && a<0.6f) || (bb2>0.f && bb2<0.6f) || (c>0.f && c<0.6f);
      bool valid = (cls==0) ? fg : !fg;
      uint32_t gi = (uint32_t)(sub*STRIP + pi);
      uint32_t r1,r2; threefry(s0, s1, 0u, gi, r1, r2);
      uint32_t vv = valid ? ((r1 ^ r2) >> 9) + 1u : 0u;  // monotone in uniform; 0 = invalid(-1.0)
      vvL[pi] = vv;
      atomicAdd(&hist[vv>>16], 1);
    }
  }
  __syncthreads();
  if(tid==0){
    int acc=0, bx=128;
    for(; bx>=0; bx--){ acc += hist[bx]; if(acc>=50) break; }
    bbin = bx;
  }
  __syncthreads();
  int bb = bbin;
  for(int r=0;r<3;r++){
    int pi = tid + r*512;
    if(pi<STRIP){
      uint32_t vv = vvL[pi];
      if((int)(vv>>16) >= bb){
        int pos = atomicAdd(&ncand,1);
        cand[pos] = ((uint64_t)vv << 14) | (uint64_t)(16383 - (sub*STRIP + pi));
      }
    }
  }
  __syncthreads();
  int m = ncand;
  for(int c=tid;c<m;c+=512){
    uint64_t k = cand[c];
    int r = 0, j = 0;
    while(j < m){                      // chunked early-exit: exact for r<50
      int je = j+64 < m ? j+64 : m;
      for(; j<je; j++) r += (cand[j] > k);
      if(r >= 50) break;
    }
    if(r < 50) key50g[(size_t)b*50 + r] = k;
  }
  __threadfence();
  __syncthreads();
  if(tid==0) atomicExch(&flagB[b], MAGIC);

  // ================= P2 (one block per image): merge 8x50 keys/class -> stats ======
  if((b & 15) == 0){
    if(tid<16){ while(atomicAdd(&flagB[img*16+tid],0)!=MAGIC) __builtin_amdgcn_s_sleep(2); }
    __syncthreads();
    __threadfence();
    for(int cl=0; cl<2; cl++){
      size_t kb = (size_t)(img*16 + cl*8)*50;
      if(tid<400) cand[tid] = key50g[kb + tid];
      __syncthreads();
      if(tid<400){
        uint64_t k = cand[tid];
        int r = 0;
        for(int j=0;j<400;j++) r += (cand[j] > k);
        if(r < 50) tIdxL[cl*50+r] = 16383 - (int)(k & 16383u);
      }
      __syncthreads();
    }
    // stats: bit-identical math to rounds 1-4
    if(tid<100){
      int pp = tIdxL[tid];
      int i=pp/96, j=pp-i*96;
      const float* px = in + ((size_t)img*NPIX + pp)*3;
      for(int c=0;c<3;c++){
        float ip=clip01_div255(px[c]);
        feat[tid][c]=ip/255.0f;
      }
      feat[tid][3]=((float)i/96.0f)*100.0f;
      feat[tid][4]=((float)j/96.0f)*100.0f;
    }
    __syncthreads();
    if(tid<5){
      float s=0.f;
      for(int r=0;r<100;r++) s=s+feat[r][tid];
      float mu=s/100.0f; mv[tid]=mu;
      float v=0.f;
      for(int r=0;r<100;r++){ float d=feat[r][tid]-mu; float q=d*d; v=v+q; }
      sv[tid]=sqrtf(v/100.0f);
    }
    __syncthreads();
    if(tid<100){
      for(int k=0;k<5;k++) train_s[(img*100+tid)*5+k]=(feat[tid][k]-mv[k])/sv[k];
    }
    if(tid<5)       meanstd[img*10+tid]=mv[tid];
    else if(tid<10) meanstd[img*10+tid]=sv[tid-5];
    __threadfence();
    __syncthreads();
    if(tid==0) atomicExch(&flagC[img], MAGIC);
  }

  // ================= P3: kknn over own 576-pixel chunk ============================
  int pbase = b * 576;                 // 512 blocks x 576 = 294912 pixels
  int img3  = b >> 4;                  // 16 blocks per image (16*576 = 9216)
  const float* cb3 = in + (size_t)pbase*3;
  // pre-stage pixels BEFORE the stats wait (overlaps P2)
  for(int k=0;k<4;k++){ int idx=k*512+tid; if(idx<1728) pixL[idx]=cb3[idx]; }
  if(tid==0){ while(atomicAdd(&flagC[img3],0)!=MAGIC) __builtin_amdgcn_s_sleep(2); }
  __syncthreads();
  __threadfence();
  if(tid<100){
    const float* tr = train_s + (img3*100+tid)*5;
    ts[tid][0]=tr[0]; ts[tid][1]=tr[1]; ts[tid][2]=tr[2]; ts[tid][3]=tr[3]; ts[tid][4]=tr[4];
  }
  if(tid>=128 && tid<133) mv[tid-128]=meanstd[img3*10+(tid-128)];
  if(tid>=160 && tid<165) sv[tid-160]=meanstd[img3*10+5+(tid-160)];
  __syncthreads();

  for(int r2=0;r2<2;r2++){
    int pl = tid + r2*512;
    if(pl < 576){
      int pim = pbase + pl - img3*NPIX;     // pixel index within image
      int i = pim/96, j = pim - i*96;
      float ip0=clip01_div255(pixL[pl*3+0]);
      float ip1=clip01_div255(pixL[pl*3+1]);
      float ip2=clip01_div255(pixL[pl*3+2]);
      float t0,t1,t2,t3,t4;
      {
        float f0=ip0/255.0f, f1=ip1/255.0f, f2=ip2/255.0f;
        float f3=((float)i/96.0f)*100.0f, f4=((float)j/96.0f)*100.0f;
        t0=(f0-mv[0])/sv[0]; t1=(f1-mv[1])/sv[1]; t2=(f2-mv[2])/sv[2];
        t3=(f3-mv[3])/sv[3]; t4=(f4-mv[4])/sv[4];
      }
      // phase A: fg neighbors 0..49, values-only sorted top-5 (exact FP order of round 4)
      float a0=1e30f,a1=1e30f,a2=1e30f,a3=1e30f,a4=1e30f;
#pragma unroll 5
      for(int jn=0;jn<50;jn++){
        float4 q = *(const float4*)&ts[jn][0];
        float  q4 = ts[jn][4];
        float s=0.f;
        { float d=t0-q.x; float w=d*d; s=s+w; }
        { float d=t1-q.y; float w=d*d; s=s+w; }
        { float d=t2-q.z; float w=d*d; s=s+w; }
        { float d=t3-q.w; float w=d*d; s=s+w; }
        { float d=t4-q4;  float w=d*d; s=s+w; }
        float d=sqrtf(s);
        bool l0=d<a0,l1=d<a1,l2=d<a2,l3=d<a3,l4=d<a4;
        a4 = l4 ? (l3?a3:d) : a4;
        a3 = l3 ? (l2?a2:d) : a3;
        a2 = l2 ? (l1?a1:d) : a2;
        a1 = l1 ? (l0?a0:d) : a1;
        a0 = l0 ? d : a0;
      }
      // phase B: bg neighbors 50..99
      float b0=1e30f,b1=1e30f,b2=1e30f,b3=1e30f,b4=1e30f;
#pragma unroll 5
      for(int jn=50;jn<100;jn++){
        float4 q = *(const float4*)&ts[jn][0];
        float  q4 = ts[jn][4];
        float s=0.f;
        { float d=t0-q.x; float w=d*d; s=s+w; }
        { float d=t1-q.y; float w=d*d; s=s+w; }
        { float d=t2-q.z; float w=d*d; s=s+w; }
        { float d=t3-q.w; float w=d*d; s=s+w; }
        { float d=t4-q4;  float w=d*d; s=s+w; }
        float d=sqrtf(s);
        bool l0=d<b0,l1=d<b1,l2=d<b2,l3=d<b3,l4=d<b4;
        b4 = l4 ? (l3?b3:d) : b4;
        b3 = l3 ? (l2?b2:d) : b3;
        b2 = l2 ? (l1?b1:d) : b2;
        b1 = l1 ? (l0?b0:d) : b1;
        b0 = l0 ? d : b0;
      }
      // merge-count: fg (idx<50) wins ties vs bg; cnt>=2 <=> mean>=0.3
      int cnt = (a0<=b4)+(a1<=b3)+(a2<=b2)+(a3<=b1)+(a4<=b0);
      bool seg = cnt>=2;
      pixL[pl*3+0]=seg?ip0:0.f;       // in-place: each thread touches only its own 3
      pixL[pl*3+1]=seg?ip1:0.f;
      pixL[pl*3+2]=seg?ip2:0.f;
    }
  }
  __syncthreads();
  float* ob = out + (size_t)pbase*3;
  for(int k=0;k<4;k++){ int idx=k*512+tid; if(idx<1728) ob[idx]=pixL[idx]; }
}

extern "C" void kernel_launch(void* const* d_in, const int* in_sizes, int n_in,
                              void* d_out, int out_size, void* d_ws, size_t ws_size,
                              hipStream_t stream) {
  const float* in = (const float*)d_in[0];
  float* out = (float*)d_out;
  // ws layout (8B-aligned where needed)
  float* maxpart = (float*)d_ws;                                    // 3072 B
  int*   flagA   = (int*)((char*)d_ws + 3072);                      // 1024 B
  int*   flagB   = (int*)((char*)d_ws + 4096);                      // 2048 B
  int*   flagC   = (int*)((char*)d_ws + 6144);                      // 128 B
  unsigned long long* key50g = (unsigned long long*)((char*)d_ws + 6272);  // 204800 B
  float* train_s = (float*)((char*)d_ws + 211072);                  // 64000 B
  float* meanstd = (float*)((char*)d_ws + 275072);                  // 1280 B

  kfused<<<512, 512, 0, stream>>>(in, out, maxpart, flagA, flagB, flagC,
                                  key50g, train_s, meanstd);
}

// Round 6
// 146.532 us; speedup vs baseline: 2.4897x; 2.4897x over previous
//
#include <hip/hip_runtime.h>
#include <stdint.h>

#define NPIX 9216   // 96*96
#define NIMG 32
#define STRIP 1152  // NPIX / 8 strips

// ---------- JAX threefry2x32 (20 rounds), bit-exact (verified rounds 1-5) ----------
__device__ __forceinline__ uint32_t rotl32(uint32_t x, int d){ return (x<<d)|(x>>(32-d)); }

__device__ __forceinline__ void threefry(uint32_t k0, uint32_t k1, uint32_t x0, uint32_t x1,
                                         uint32_t &o0, uint32_t &o1){
  uint32_t ks2 = k0 ^ k1 ^ 0x1BD11BDAu;
  x0 += k0; x1 += k1;
  x0+=x1; x1=rotl32(x1,13); x1^=x0;
  x0+=x1; x1=rotl32(x1,15); x1^=x0;
  x0+=x1; x1=rotl32(x1,26); x1^=x0;
  x0+=x1; x1=rotl32(x1,6);  x1^=x0;
  x0+=k1; x1+=ks2+1u;
  x0+=x1; x1=rotl32(x1,17); x1^=x0;
  x0+=x1; x1=rotl32(x1,29); x1^=x0;
  x0+=x1; x1=rotl32(x1,16); x1^=x0;
  x0+=x1; x1=rotl32(x1,24); x1^=x0;
  x0+=ks2; x1+=k0+2u;
  x0+=x1; x1=rotl32(x1,13); x1^=x0;
  x0+=x1; x1=rotl32(x1,15); x1^=x0;
  x0+=x1; x1=rotl32(x1,26); x1^=x0;
  x0+=x1; x1=rotl32(x1,6);  x1^=x0;
  x0+=k0; x1+=k1+3u;
  x0+=x1; x1=rotl32(x1,17); x1^=x0;
  x0+=x1; x1=rotl32(x1,29); x1^=x0;
  x0+=x1; x1=rotl32(x1,16); x1^=x0;
  x0+=x1; x1=rotl32(x1,24); x1^=x0;
  x0+=k1; x1+=ks2+4u;
  x0+=x1; x1=rotl32(x1,13); x1^=x0;
  x0+=x1; x1=rotl32(x1,15); x1^=x0;
  x0+=x1; x1=rotl32(x1,26); x1^=x0;
  x0+=x1; x1=rotl32(x1,6);  x1^=x0;
  x0+=ks2; x1+=k0+5u;
  o0=x0; o1=x1;
}

__device__ __forceinline__ float clip01_div255(float x){
  return fminf(fmaxf(x/255.0f, 0.0f), 1.0f);
}

// ---------- K1: 512 blocks = img x cls x 8 strips. Redundant per-image channel max
// (fmax exactly associative), score own strip, exact local top-50 keys ----------
__global__ __launch_bounds__(256) void kscore(const float* __restrict__ in,
                                              unsigned long long* __restrict__ key50g){
#pragma clang fp contract(off)
  int b   = blockIdx.x;                 // img*16 + cls*8 + sub
  int img = b >> 4, cls = (b >> 3) & 1, sub = b & 7;
  int tid = threadIdx.x;
  int lane = tid & 63, wv = tid >> 6;

  __shared__ __attribute__((aligned(16))) float pixL[3456];  // strip pixels
  __shared__ uint32_t vvL[STRIP];
  __shared__ uint64_t cand[STRIP];
  __shared__ int hist[129];
  __shared__ int ncand, bbin;
  __shared__ float red[3][4];
  __shared__ float bcast[3];

  if(tid<129) hist[tid]=0;
  if(tid==0)  ncand=0;

  const float* p = in + (size_t)img*NPIX*3;

  // stage own strip (float4 coalesced: 864 float4)
  const float4* sp4 = (const float4*)(p + (size_t)sub*STRIP*3);
  float4* pixL4 = (float4*)pixL;
  for(int k=0;k<4;k++){ int i4=k*256+tid; if(i4<864) pixL4[i4]=sp4[i4]; }

  // full-image channel max (float4, branchless channel select)
  float m0=0.f,m1=0.f,m2=0.f;
  const float4* p4 = (const float4*)p;   // 6912 float4
#pragma unroll 3
  for(int k=0;k<27;k++){
    int i4 = k*256+tid;
    float4 v = p4[i4];
    int c = i4 % 3;                      // channel of element0 = (4*i4)%3 = i4%3
    float e0=clip01_div255(v.x), e1=clip01_div255(v.y);
    float e2=clip01_div255(v.z), e3=clip01_div255(v.w);
    bool is0=(c==0), is1=(c==1);
    float ex = fmaxf(e0,e3);             // both land on channel c
    m0 = fmaxf(m0, is0?ex:(is1?e2:e1));
    m1 = fmaxf(m1, is0?e1:(is1?ex:e2));
    m2 = fmaxf(m2, is0?e2:(is1?e1:ex));
  }
  for(int off=32;off>0;off>>=1){
    m0=fmaxf(m0,__shfl_down(m0,off));
    m1=fmaxf(m1,__shfl_down(m1,off));
    m2=fmaxf(m2,__shfl_down(m2,off));
  }
  if(lane==0){ red[0][wv]=m0; red[1][wv]=m1; red[2][wv]=m2; }
  __syncthreads();
  if(tid==0){
    bcast[0]=fmaxf(fmaxf(red[0][0],red[0][1]),fmaxf(red[0][2],red[0][3]));
    bcast[1]=fmaxf(fmaxf(red[1][0],red[1][1]),fmaxf(red[1][2],red[1][3]));
    bcast[2]=fmaxf(fmaxf(red[2][0],red[2][1]),fmaxf(red[2][2],red[2][3]));
  }
  __syncthreads();
  float c0=bcast[0], c1=bcast[1], c2=bcast[2];

  // partitionable threefry keys (bit-exact)
  uint32_t ik0, ik1; threefry(0u, 42u, 0u, (uint32_t)img, ik0, ik1);
  uint32_t s0, s1;   threefry(ik0, ik1, 0u, (uint32_t)cls, s0, s1);

  // score strip + histogram
  for(int r=0;r<5;r++){
    int pi = tid + r*256;
    if(pi<STRIP){
      float a  = clip01_div255(pixL[pi*3+0])/c0;
      float bb = clip01_div255(pixL[pi*3+1])/c1;
      float c  = clip01_div255(pixL[pi*3+2])/c2;
      bool fg = (a>0.f && a<0.6f) || (bb>0.f && bb<0.6f) || (c>0.f && c<0.6f);
      bool valid = (cls==0) ? fg : !fg;
      uint32_t gi = (uint32_t)(sub*STRIP + pi);
      uint32_t r1,r2; threefry(s0, s1, 0u, gi, r1, r2);
      uint32_t vv = valid ? ((r1 ^ r2) >> 9) + 1u : 0u;  // monotone in uniform; 0 = invalid(-1.0)
      vvL[pi] = vv;
      atomicAdd(&hist[vv>>16], 1);
    }
  }
  __syncthreads();
  if(tid==0){
    int acc=0, bx=128;
    for(; bx>=0; bx--){ acc += hist[bx]; if(acc>=50) break; }
    bbin = bx;                           // strip has 1152 keys total -> always reaches 50
  }
  __syncthreads();
  int bb = bbin;
  for(int r=0;r<5;r++){
    int pi = tid + r*256;
    if(pi<STRIP){
      uint32_t vv = vvL[pi];
      if((int)(vv>>16) >= bb){
        int pos = atomicAdd(&ncand,1);
        cand[pos] = ((uint64_t)vv << 14) | (uint64_t)(16383 - (sub*STRIP + pi));  // higher = earlier
      }
    }
  }
  __syncthreads();
  int m = ncand;
  for(int c=tid;c<m;c+=256){
    uint64_t k = cand[c];
    int r = 0, j = 0;
    while(j < m){                        // chunked early-exit: exact for r<50
      int je = j+64 < m ? j+64 : m;
      for(; j<je; j++) r += (cand[j] > k);
      if(r >= 50) break;
    }
    if(r < 50) key50g[(size_t)b*50 + r] = k;  // rank r -> descending sorted list
  }
}

// ---------- K2: 1152 blocks = img x 36 chunks. Redundant merge (bsearch over 8
// sorted strip lists) + stats, then 5-NN with d^2 top-(a1,b3) and 2 sqrts ----------
__global__ __launch_bounds__(256) void kknn(const float* __restrict__ in,
                                            const unsigned long long* __restrict__ key50g,
                                            float* __restrict__ out){
#pragma clang fp contract(off)
  int b     = blockIdx.x;
  int img   = b / 36;
  int chunk = b % 36;
  int tid   = threadIdx.x;

  __shared__ uint64_t kk[800];           // both classes' 16 strip lists
  __shared__ int      tIdx[100];
  __shared__ float    feat[100][5];
  __shared__ float    mv[5], sv[5];
  __shared__ __attribute__((aligned(16))) float ts2[50*12];  // pair-packed train rows
  __shared__ __attribute__((aligned(16))) float pix[768];

  // load merged key block (contiguous 800 uint64) + stage own pixel chunk
  const uint64_t* kg = (const uint64_t*)key50g + (size_t)img*800;
  for(int c=tid;c<800;c+=256) kk[c] = kg[c];
  {
    const float4* cb4 = (const float4*)(in + ((size_t)img*NPIX + (size_t)chunk*256)*3);
    if(tid<192) ((float4*)pix)[tid] = cb4[tid];
  }
  __syncthreads();

  // merge: global rank of each key within its class via binary search on the
  // 8 descending 50-lists (count of strictly-greater keys; keys unique)
  for(int c=tid;c<800;c+=256){
    uint64_t k = kk[c];
    int cl = (c >= 400);
    int base = cl*400;
    int r = 0;
#pragma unroll
    for(int s=0;s<8;s++){
      const uint64_t* L = &kk[base + s*50];
      int lo=0, hi=50;
      while(lo<hi){ int mid=(lo+hi)>>1; if(L[mid] > k) lo=mid+1; else hi=mid; }
      r += lo;
    }
    if(r < 50) tIdx[cl*50+r] = 16383 - (int)(k & 16383u);
  }
  __syncthreads();

  // train features (math bit-identical to rounds 1-5)
  if(tid<100){
    int pp = tIdx[tid];
    int i=pp/96, j=pp-i*96;
    const float* px = in + ((size_t)img*NPIX + pp)*3;
    for(int c=0;c<3;c++){
      float ip=clip01_div255(px[c]);
      feat[tid][c]=ip/255.0f;
    }
    feat[tid][3]=((float)i/96.0f)*100.0f;
    feat[tid][4]=((float)j/96.0f)*100.0f;
  }
  __syncthreads();
  if(tid<5){
    float s=0.f;
    for(int r=0;r<100;r++) s=s+feat[r][tid];
    float mu=s/100.0f; mv[tid]=mu;
    float v=0.f;
    for(int r=0;r<100;r++){ float d=feat[r][tid]-mu; float q=d*d; v=v+q; }
    sv[tid]=sqrtf(v/100.0f);
  }
  __syncthreads();
  // standardize into pair-packed layout: pair p holds rows 2p (f0..4) and 2p+1 (f5..9), pad 2
  if(tid<100){
    float r0=(feat[tid][0]-mv[0])/sv[0];
    float r1=(feat[tid][1]-mv[1])/sv[1];
    float r2=(feat[tid][2]-mv[2])/sv[2];
    float r3=(feat[tid][3]-mv[3])/sv[3];
    float r4=(feat[tid][4]-mv[4])/sv[4];
    float* dst = &ts2[(tid>>1)*12 + (tid&1)*5];
    dst[0]=r0; dst[1]=r1; dst[2]=r2; dst[3]=r3; dst[4]=r4;
  }
  __syncthreads();

  // test feature for own pixel
  int p = chunk*256+tid;
  int i=p/96, j=p-i*96;
  float ip0=clip01_div255(pix[tid*3+0]);
  float ip1=clip01_div255(pix[tid*3+1]);
  float ip2=clip01_div255(pix[tid*3+2]);
  float t0,t1,t2,t3,t4;
  {
    float f0=ip0/255.0f, f1=ip1/255.0f, f2=ip2/255.0f;
    float f3=((float)i/96.0f)*100.0f, f4=((float)j/96.0f)*100.0f;
    t0=(f0-mv[0])/sv[0]; t1=(f1-mv[1])/sv[1]; t2=(f2-mv[2])/sv[2];
    t3=(f3-mv[3])/sv[3]; t4=(f4-mv[4])/sv[4];
  }

  // seg <=> (2nd-smallest fg dist) <= (4th-smallest bg dist)  [monotone merge-count,
  // equivalent to round-4's cnt>=2]. Intra-class selection in d^2 (sqrt monotone ->
  // identical multisets); sqrt applied only to the two finalists, ties: fg wins (<=).
  float a0=1e30f,a1=1e30f;               // fg d^2 smallest two
#pragma unroll 5
  for(int pr=0;pr<25;pr++){
    const float* tp = &ts2[pr*12];
    float4 qa = *(const float4*)(tp);    // r0: f0..f3
    float4 qb = *(const float4*)(tp+4);  // r0f4 | r1: f0..f2
    float2 qc = *(const float2*)(tp+8);  // r1: f3,f4
    {
      float s;
      { float d=t0-qa.x; s=d*d; }
      { float d=t1-qa.y; float w=d*d; s=s+w; }
      { float d=t2-qa.z; float w=d*d; s=s+w; }
      { float d=t3-qa.w; float w=d*d; s=s+w; }
      { float d=t4-qb.x; float w=d*d; s=s+w; }
      bool l0=s<a0,l1=s<a1;
      a1 = l1 ? (l0?a0:s) : a1;
      a0 = l0 ? s : a0;
    }
    {
      float s;
      { float d=t0-qb.y; s=d*d; }
      { float d=t1-qb.z; float w=d*d; s=s+w; }
      { float d=t2-qb.w; float w=d*d; s=s+w; }
      { float d=t3-qc.x; float w=d*d; s=s+w; }
      { float d=t4-qc.y; float w=d*d; s=s+w; }
      bool l0=s<a0,l1=s<a1;
      a1 = l1 ? (l0?a0:s) : a1;
      a0 = l0 ? s : a0;
    }
  }
  float b0=1e30f,b1=1e30f,b2=1e30f,b3=1e30f;   // bg d^2 smallest four
#pragma unroll 5
  for(int pr=25;pr<50;pr++){
    const float* tp = &ts2[pr*12];
    float4 qa = *(const float4*)(tp);
    float4 qb = *(const float4*)(tp+4);
    float2 qc = *(const float2*)(tp+8);
    {
      float s;
      { float d=t0-qa.x; s=d*d; }
      { float d=t1-qa.y; float w=d*d; s=s+w; }
      { float d=t2-qa.z; float w=d*d; s=s+w; }
      { float d=t3-qa.w; float w=d*d; s=s+w; }
      { float d=t4-qb.x; float w=d*d; s=s+w; }
      bool l0=s<b0,l1=s<b1,l2=s<b2,l3=s<b3;
      b3 = l3 ? (l2?b2:s) : b3;
      b2 = l2 ? (l1?b1:s) : b2;
      b1 = l1 ? (l0?b0:s) : b1;
      b0 = l0 ? s : b0;
    }
    {
      float s;
      { float d=t0-qb.y; s=d*d; }
      { float d=t1-qb.z; float w=d*d; s=s+w; }
      { float d=t2-qb.w; float w=d*d; s=s+w; }
      { float d=t3-qc.x; float w=d*d; s=s+w; }
      { float d=t4-qc.y; float w=d*d; s=s+w; }
      bool l0=s<b0,l1=s<b1,l2=s<b2,l3=s<b3;
      b3 = l3 ? (l2?b2:s) : b3;
      b2 = l2 ? (l1?b1:s) : b2;
      b1 = l1 ? (l0?b0:s) : b1;
      b0 = l0 ? s : b0;
    }
  }
  bool seg = sqrtf(a1) <= sqrtf(b3);
  __syncthreads();                       // pix reuse fence
  pix[tid*3+0]=seg?ip0:0.f;
  pix[tid*3+1]=seg?ip1:0.f;
  pix[tid*3+2]=seg?ip2:0.f;
  __syncthreads();
  float4* ob4 = (float4*)(out + ((size_t)img*NPIX + (size_t)chunk*256)*3);
  if(tid<192) ob4[tid] = ((float4*)pix)[tid];
}

extern "C" void kernel_launch(void* const* d_in, const int* in_sizes, int n_in,
                              void* d_out, int out_size, void* d_ws, size_t ws_size,
                              hipStream_t stream) {
  const float* in = (const float*)d_in[0];
  float* out = (float*)d_out;
  unsigned long long* key50g = (unsigned long long*)d_ws;   // 512*50*8 = 204800 B

  kscore<<<512,  256, 0, stream>>>(in, key50g);
  kknn  <<<1152, 256, 0, stream>>>(in, key50g, out);
}

// Round 7
// 113.635 us; speedup vs baseline: 3.2105x; 1.2895x over previous
//
#include <hip/hip_runtime.h>
#include <stdint.h>

#define NPIX 9216   // 96*96
#define NIMG 32
#define STRIP 1152  // NPIX / 8 strips

// ---------- JAX threefry2x32 (20 rounds), bit-exact (verified rounds 1-6) ----------
__device__ __forceinline__ uint32_t rotl32(uint32_t x, int d){ return (x<<d)|(x>>(32-d)); }

__device__ __forceinline__ void threefry(uint32_t k0, uint32_t k1, uint32_t x0, uint32_t x1,
                                         uint32_t &o0, uint32_t &o1){
  uint32_t ks2 = k0 ^ k1 ^ 0x1BD11BDAu;
  x0 += k0; x1 += k1;
  x0+=x1; x1=rotl32(x1,13); x1^=x0;
  x0+=x1; x1=rotl32(x1,15); x1^=x0;
  x0+=x1; x1=rotl32(x1,26); x1^=x0;
  x0+=x1; x1=rotl32(x1,6);  x1^=x0;
  x0+=k1; x1+=ks2+1u;
  x0+=x1; x1=rotl32(x1,17); x1^=x0;
  x0+=x1; x1=rotl32(x1,29); x1^=x0;
  x0+=x1; x1=rotl32(x1,16); x1^=x0;
  x0+=x1; x1=rotl32(x1,24); x1^=x0;
  x0+=ks2; x1+=k0+2u;
  x0+=x1; x1=rotl32(x1,13); x1^=x0;
  x0+=x1; x1=rotl32(x1,15); x1^=x0;
  x0+=x1; x1=rotl32(x1,26); x1^=x0;
  x0+=x1; x1=rotl32(x1,6);  x1^=x0;
  x0+=k0; x1+=k1+3u;
  x0+=x1; x1=rotl32(x1,17); x1^=x0;
  x0+=x1; x1=rotl32(x1,29); x1^=x0;
  x0+=x1; x1=rotl32(x1,16); x1^=x0;
  x0+=x1; x1=rotl32(x1,24); x1^=x0;
  x0+=k1; x1+=ks2+4u;
  x0+=x1; x1=rotl32(x1,13); x1^=x0;
  x0+=x1; x1=rotl32(x1,15); x1^=x0;
  x0+=x1; x1=rotl32(x1,26); x1^=x0;
  x0+=x1; x1=rotl32(x1,6);  x1^=x0;
  x0+=ks2; x1+=k0+5u;
  o0=x0; o1=x1;
}

__device__ __forceinline__ float clip01_div255(float x){
  return fminf(fmaxf(x/255.0f, 0.0f), 1.0f);
}

// ---------- K0: partial channel max, 6 blocks/image, plain partial stores ----------
__global__ __launch_bounds__(256) void kmax(const float* __restrict__ in,
                                            float* __restrict__ maxpart){
  int img  = blockIdx.x / 6;
  int part = blockIdx.x % 6;
  int tid  = threadIdx.x;
  const float* base = in + (size_t)img*NPIX*3 + (size_t)part*1536*3;
  float m0=0.f, m1=0.f, m2=0.f;
#pragma unroll
  for(int k=0;k<18;k++){
    int g = k*256 + tid;
    float v = clip01_div255(base[g]);
    int c = g % 3;
    m0 = (c==0) ? fmaxf(m0,v) : m0;
    m1 = (c==1) ? fmaxf(m1,v) : m1;
    m2 = (c==2) ? fmaxf(m2,v) : m2;
  }
  for(int off=32; off>0; off>>=1){
    m0 = fmaxf(m0, __shfl_down(m0,off));
    m1 = fmaxf(m1, __shfl_down(m1,off));
    m2 = fmaxf(m2, __shfl_down(m2,off));
  }
  __shared__ float r[3][4];
  int lane = tid & 63, wv = tid >> 6;
  if(lane==0){ r[0][wv]=m0; r[1][wv]=m1; r[2][wv]=m2; }
  __syncthreads();
  if(tid==0){
    maxpart[blockIdx.x*3+0]=fmaxf(fmaxf(r[0][0],r[0][1]),fmaxf(r[0][2],r[0][3]));
    maxpart[blockIdx.x*3+1]=fmaxf(fmaxf(r[1][0],r[1][1]),fmaxf(r[1][2],r[1][3]));
    maxpart[blockIdx.x*3+2]=fmaxf(fmaxf(r[2][0],r[2][1]),fmaxf(r[2][2],r[2][3]));
  }
}

// ---------- K1: 512 blocks = img x cls x 8 strips: score strip, exact local top-50 --
__global__ __launch_bounds__(256) void kscore(const float* __restrict__ in,
                                              const float* __restrict__ maxpart,
                                              unsigned long long* __restrict__ key50g){
#pragma clang fp contract(off)
  int b   = blockIdx.x;                 // img*16 + cls*8 + sub
  int img = b >> 4, cls = (b >> 3) & 1, sub = b & 7;
  int tid = threadIdx.x;

  __shared__ __attribute__((aligned(16))) float pixL[3456];  // strip pixels
  __shared__ uint32_t vvL[STRIP];
  __shared__ uint64_t cand[STRIP];
  __shared__ int hist[129];
  __shared__ int ncand, bbin;

  if(tid<129) hist[tid]=0;
  if(tid==0)  ncand=0;

  const float* p = in + (size_t)img*NPIX*3;

  // stage own strip (float4 coalesced: 864 float4)
  const float4* sp4 = (const float4*)(p + (size_t)sub*STRIP*3);
  float4* pixL4 = (float4*)pixL;
  for(int k=0;k<4;k++){ int i4=k*256+tid; if(i4<864) pixL4[i4]=sp4[i4]; }

  // fold 6 partial maxes (uniform -> scalar loads; fmax exactly associative)
  float c0=0.f,c1=0.f,c2=0.f;
#pragma unroll
  for(int s=0;s<6;s++){
    c0=fmaxf(c0, maxpart[(img*6+s)*3+0]);
    c1=fmaxf(c1, maxpart[(img*6+s)*3+1]);
    c2=fmaxf(c2, maxpart[(img*6+s)*3+2]);
  }

  // partitionable threefry keys (bit-exact)
  uint32_t ik0, ik1; threefry(0u, 42u, 0u, (uint32_t)img, ik0, ik1);
  uint32_t s0, s1;   threefry(ik0, ik1, 0u, (uint32_t)cls, s0, s1);
  __syncthreads();

  // score strip + histogram
  for(int r=0;r<5;r++){
    int pi = tid + r*256;
    if(pi<STRIP){
      float a  = clip01_div255(pixL[pi*3+0])/c0;
      float bb = clip01_div255(pixL[pi*3+1])/c1;
      float c  = clip01_div255(pixL[pi*3+2])/c2;
      bool fg = (a>0.f && a<0.6f) || (bb>0.f && bb<0.6f) || (c>0.f && c<0.6f);
      bool valid = (cls==0) ? fg : !fg;
      uint32_t gi = (uint32_t)(sub*STRIP + pi);
      uint32_t r1,r2; threefry(s0, s1, 0u, gi, r1, r2);
      uint32_t vv = valid ? ((r1 ^ r2) >> 9) + 1u : 0u;  // monotone in uniform; 0 = invalid(-1.0)
      vvL[pi] = vv;
      atomicAdd(&hist[vv>>16], 1);
    }
  }
  __syncthreads();
  if(tid==0){
    int acc=0, bx=128;
    for(; bx>=0; bx--){ acc += hist[bx]; if(acc>=50) break; }
    bbin = bx;                           // strip has 1152 keys total -> always reaches 50
  }
  __syncthreads();
  int bb = bbin;
  for(int r=0;r<5;r++){
    int pi = tid + r*256;
    if(pi<STRIP){
      uint32_t vv = vvL[pi];
      if((int)(vv>>16) >= bb){
        int pos = atomicAdd(&ncand,1);
        cand[pos] = ((uint64_t)vv << 14) | (uint64_t)(16383 - (sub*STRIP + pi));  // higher = earlier
      }
    }
  }
  __syncthreads();
  int m = ncand;
  for(int c=tid;c<m;c+=256){
    uint64_t k = cand[c];
    int r = 0, j = 0;
    while(j < m){                        // chunked early-exit: exact for r<50
      int je = j+64 < m ? j+64 : m;
      for(; j<je; j++) r += (cand[j] > k);
      if(r >= 50) break;
    }
    if(r < 50) key50g[(size_t)b*50 + r] = k;  // rank r -> descending sorted list
  }
}

// ---------- K2 (32 blocks): merge 16 strip lists -> top-50/class -> stats -> pack ---
__global__ __launch_bounds__(256) void kmerge(const float* __restrict__ in,
                                              const unsigned long long* __restrict__ key50g,
                                              float* __restrict__ ts2g,      // [32][600]
                                              float* __restrict__ meanstd){  // [32][10]
#pragma clang fp contract(off)
  int img = blockIdx.x;
  int tid = threadIdx.x;
  __shared__ uint64_t kk[800];
  __shared__ int      tIdx[100];
  __shared__ float    feat[100][5];
  __shared__ float    mv[5], sv[5];

  const uint64_t* kg = (const uint64_t*)key50g + (size_t)img*800;
  for(int c=tid;c<800;c+=256) kk[c] = kg[c];
  __syncthreads();

  // global rank of each key within its class via binary search on the
  // 8 descending 50-lists (count of strictly-greater keys; keys unique)
  for(int c=tid;c<800;c+=256){
    uint64_t k = kk[c];
    int cl = (c >= 400);
    int base = cl*400;
    int r = 0;
#pragma unroll
    for(int s=0;s<8;s++){
      const uint64_t* L = &kk[base + s*50];
      int lo=0, hi=50;
      while(lo<hi){ int mid=(lo+hi)>>1; if(L[mid] > k) lo=mid+1; else hi=mid; }
      r += lo;
    }
    if(r < 50) tIdx[cl*50+r] = 16383 - (int)(k & 16383u);
  }
  __syncthreads();

  // train features + stats (math bit-identical to rounds 1-6)
  if(tid<100){
    int pp = tIdx[tid];
    int i=pp/96, j=pp-i*96;
    const float* px = in + ((size_t)img*NPIX + pp)*3;
    for(int c=0;c<3;c++){
      float ip=clip01_div255(px[c]);
      feat[tid][c]=ip/255.0f;
    }
    feat[tid][3]=((float)i/96.0f)*100.0f;
    feat[tid][4]=((float)j/96.0f)*100.0f;
  }
  __syncthreads();
  if(tid<5){
    float s=0.f;
    for(int r=0;r<100;r++) s=s+feat[r][tid];
    float mu=s/100.0f; mv[tid]=mu;
    float v=0.f;
    for(int r=0;r<100;r++){ float d=feat[r][tid]-mu; float q=d*d; v=v+q; }
    sv[tid]=sqrtf(v/100.0f);
  }
  __syncthreads();
  // standardize into pair-packed layout: pair p holds rows 2p (f0..4), 2p+1 (f5..9), pad 2
  if(tid<100){
    float r0=(feat[tid][0]-mv[0])/sv[0];
    float r1=(feat[tid][1]-mv[1])/sv[1];
    float r2=(feat[tid][2]-mv[2])/sv[2];
    float r3=(feat[tid][3]-mv[3])/sv[3];
    float r4=(feat[tid][4]-mv[4])/sv[4];
    float* dst = ts2g + img*600 + (tid>>1)*12 + (tid&1)*5;
    dst[0]=r0; dst[1]=r1; dst[2]=r2; dst[3]=r3; dst[4]=r4;
  }
  if(tid<5)       meanstd[img*10+tid]=mv[tid];
  else if(tid<10) meanstd[img*10+tid]=sv[tid-5];
}

// ---------- K3: 1152 blocks = img x 36 chunks: lean 5-NN (d^2 a1/b3, 2 sqrts) ------
__global__ __launch_bounds__(256) void kknn(const float* __restrict__ in,
                                            const float* __restrict__ ts2g,
                                            const float* __restrict__ meanstd,
                                            float* __restrict__ out){
#pragma clang fp contract(off)
  int b     = blockIdx.x;
  int img   = b / 36;
  int chunk = b % 36;
  int tid   = threadIdx.x;

  __shared__ float    mv[5], sv[5];
  __shared__ __attribute__((aligned(16))) float ts2[600];  // pair-packed train rows
  __shared__ __attribute__((aligned(16))) float pix[768];

  if(tid<150) ((float4*)ts2)[tid] = ((const float4*)(ts2g + img*600))[tid];
  if(tid>=192 && tid<197) mv[tid-192]=meanstd[img*10+(tid-192)];
  if(tid>=224 && tid<229) sv[tid-224]=meanstd[img*10+5+(tid-224)];
  {
    const float4* cb4 = (const float4*)(in + ((size_t)img*NPIX + (size_t)chunk*256)*3);
    if(tid<192) ((float4*)pix)[tid] = cb4[tid];
  }
  __syncthreads();

  // test feature for own pixel (bit-identical math)
  int p = chunk*256+tid;
  int i=p/96, j=p-i*96;
  float ip0=clip01_div255(pix[tid*3+0]);
  float ip1=clip01_div255(pix[tid*3+1]);
  float ip2=clip01_div255(pix[tid*3+2]);
  float t0,t1,t2,t3,t4;
  {
    float f0=ip0/255.0f, f1=ip1/255.0f, f2=ip2/255.0f;
    float f3=((float)i/96.0f)*100.0f, f4=((float)j/96.0f)*100.0f;
    t0=(f0-mv[0])/sv[0]; t1=(f1-mv[1])/sv[1]; t2=(f2-mv[2])/sv[2];
    t3=(f3-mv[3])/sv[3]; t4=(f4-mv[4])/sv[4];
  }

  // seg <=> (2nd-smallest fg dist) <= (4th-smallest bg dist); intra-class selection
  // in d^2 (sqrt monotone), sqrt only on finalists; fg wins ties (<=). [R6-verified]
  float a0=1e30f,a1=1e30f;               // fg d^2 smallest two
#pragma unroll 5
  for(int pr=0;pr<25;pr++){
    const float* tp = &ts2[pr*12];
    float4 qa = *(const float4*)(tp);    // r0: f0..f3
    float4 qb = *(const float4*)(tp+4);  // r0f4 | r1: f0..f2
    float2 qc = *(const float2*)(tp+8);  // r1: f3,f4
    {
      float s;
      { float d=t0-qa.x; s=d*d; }
      { float d=t1-qa.y; float w=d*d; s=s+w; }
      { float d=t2-qa.z; float w=d*d; s=s+w; }
      { float d=t3-qa.w; float w=d*d; s=s+w; }
      { float d=t4-qb.x; float w=d*d; s=s+w; }
      bool l0=s<a0,l1=s<a1;
      a1 = l1 ? (l0?a0:s) : a1;
      a0 = l0 ? s : a0;
    }
    {
      float s;
      { float d=t0-qb.y; s=d*d; }
      { float d=t1-qb.z; float w=d*d; s=s+w; }
      { float d=t2-qb.w; float w=d*d; s=s+w; }
      { float d=t3-qc.x; float w=d*d; s=s+w; }
      { float d=t4-qc.y; float w=d*d; s=s+w; }
      bool l0=s<a0,l1=s<a1;
      a1 = l1 ? (l0?a0:s) : a1;
      a0 = l0 ? s : a0;
    }
  }
  float b0=1e30f,b1=1e30f,b2=1e30f,b3=1e30f;   // bg d^2 smallest four
#pragma unroll 5
  for(int pr=25;pr<50;pr++){
    const float* tp = &ts2[pr*12];
    float4 qa = *(const float4*)(tp);
    float4 qb = *(const float4*)(tp+4);
    float2 qc = *(const float2*)(tp+8);
    {
      float s;
      { float d=t0-qa.x; s=d*d; }
      { float d=t1-qa.y; float w=d*d; s=s+w; }
      { float d=t2-qa.z; float w=d*d; s=s+w; }
      { float d=t3-qa.w; float w=d*d; s=s+w; }
      { float d=t4-qb.x; float w=d*d; s=s+w; }
      bool l0=s<b0,l1=s<b1,l2=s<b2,l3=s<b3;
      b3 = l3 ? (l2?b2:s) : b3;
      b2 = l2 ? (l1?b1:s) : b2;
      b1 = l1 ? (l0?b0:s) : b1;
      b0 = l0 ? s : b0;
    }
    {
      float s;
      { float d=t0-qb.y; s=d*d; }
      { float d=t1-qb.z; float w=d*d; s=s+w; }
      { float d=t2-qb.w; float w=d*d; s=s+w; }
      { float d=t3-qc.x; float w=d*d; s=s+w; }
      { float d=t4-qc.y; float w=d*d; s=s+w; }
      bool l0=s<b0,l1=s<b1,l2=s<b2,l3=s<b3;
      b3 = l3 ? (l2?b2:s) : b3;
      b2 = l2 ? (l1?b1:s) : b2;
      b1 = l1 ? (l0?b0:s) : b1;
      b0 = l0 ? s : b0;
    }
  }
  bool seg = sqrtf(a1) <= sqrtf(b3);
  __syncthreads();                       // pix reuse fence
  pix[tid*3+0]=seg?ip0:0.f;
  pix[tid*3+1]=seg?ip1:0.f;
  pix[tid*3+2]=seg?ip2:0.f;
  __syncthreads();
  float4* ob4 = (float4*)(out + ((size_t)img*NPIX + (size_t)chunk*256)*3);
  if(tid<192) ob4[tid] = ((float4*)pix)[tid];
}

extern "C" void kernel_launch(void* const* d_in, const int* in_sizes, int n_in,
                              void* d_out, int out_size, void* d_ws, size_t ws_size,
                              hipStream_t stream) {
  const float* in = (const float*)d_in[0];
  float* out = (float*)d_out;
  float* maxpart = (float*)d_ws;                                        // 192*3*4 = 2304 B
  unsigned long long* key50g = (unsigned long long*)((char*)d_ws + 2304);   // 204800 B
  float* ts2g    = (float*)((char*)d_ws + 207104);                      // 32*600*4 = 76800 B
  float* meanstd = (float*)((char*)d_ws + 283904);                      // 1280 B

  kmax  <<<192,  256, 0, stream>>>(in, maxpart);
  kscore<<<512,  256, 0, stream>>>(in, maxpart, key50g);
  kmerge<<<32,   256, 0, stream>>>(in, key50g, ts2g, meanstd);
  kknn  <<<1152, 256, 0, stream>>>(in, ts2g, meanstd, out);
}